// Round 1
// baseline (788.223 us; speedup 1.0000x reference)
//
#include <hip/hip_runtime.h>

#define N_TOTAL 204800
#define NB 1024
#define DIM 512
#define NC 52
#define BN_EPS 1e-5f

// ---------------- K0: prefix-scan of counts + dtype detect + zero stats ----
__global__ __launch_bounds__(1024) void k_scan(const int* __restrict__ bnn,
                                               int* __restrict__ offs,
                                               int* __restrict__ cnt,
                                               float* __restrict__ inv,
                                               float* __restrict__ stats /*2048 floats*/) {
    __shared__ int red[1024];
    int tid = threadIdx.x;
    int v32 = bnn[tid];
    red[tid] = v32;
    __syncthreads();
    for (int s = 512; s > 0; s >>= 1) {
        if (tid < s) red[tid] += red[tid + s];
        __syncthreads();
    }
    int total = red[0];
    __syncthreads();
    // if buffer is really int64 little-endian, low words sit at even int32 slots
    int c = (total == N_TOTAL) ? v32 : bnn[2 * tid];
    // inclusive Hillis-Steele scan
    red[tid] = c;
    __syncthreads();
    for (int off = 1; off < 1024; off <<= 1) {
        int t = (tid >= off) ? red[tid - off] : 0;
        __syncthreads();
        red[tid] += t;
        __syncthreads();
    }
    offs[tid] = red[tid] - c;   // exclusive
    cnt[tid]  = c;
    inv[tid]  = 1.0f / (float)c;
    stats[tid]        = 0.0f;   // zero s1a,s2a,s1b,s2b (2048 floats)
    stats[tid + 1024] = 0.0f;
}

// ---------------- K1: segment-mean pooling --------------------------------
__global__ __launch_bounds__(512) void k_pool(const float* __restrict__ z,
                                              const int* __restrict__ offs,
                                              const int* __restrict__ cnt,
                                              const float* __restrict__ inv,
                                              float* __restrict__ X) {
    int g = blockIdx.x;
    int s0 = offs[g];
    int n  = cnt[g];
    float r = inv[g];
    const float* p = z + (size_t)s0 * DIM + threadIdx.x;
    float a0 = 0.f, a1 = 0.f, a2 = 0.f, a3 = 0.f;
    int i = 0;
    for (; i + 4 <= n; i += 4) {
        a0 += p[(size_t)(i + 0) * DIM];
        a1 += p[(size_t)(i + 1) * DIM];
        a2 += p[(size_t)(i + 2) * DIM];
        a3 += p[(size_t)(i + 3) * DIM];
    }
    for (; i < n; i++) a0 += p[(size_t)i * DIM];
    X[(size_t)g * DIM + threadIdx.x] = (a0 + a1 + a2 + a3) * r;
}

// ---------------- K2: GEMM (1024x512 @ 512x512) + bias --------------------
__global__ __launch_bounds__(512) void k_gemm512(const float* __restrict__ A,
                                                 const float* __restrict__ W,
                                                 const float* __restrict__ bias,
                                                 float* __restrict__ Y) {
    __shared__ float As[4][DIM];
    int r0 = blockIdx.x * 4;
    int tid = threadIdx.x;
#pragma unroll
    for (int j = 0; j < 4; j++) As[j][tid] = A[(size_t)(r0 + j) * DIM + tid];
    __syncthreads();
    float acc0 = 0.f, acc1 = 0.f, acc2 = 0.f, acc3 = 0.f;
    const float* wp = W + tid;
#pragma unroll 4
    for (int k = 0; k < DIM; k++) {
        float w = wp[(size_t)k * DIM];
        acc0 += As[0][k] * w;
        acc1 += As[1][k] * w;
        acc2 += As[2][k] * w;
        acc3 += As[3][k] * w;
    }
    float b = bias[tid];
    Y[(size_t)(r0 + 0) * DIM + tid] = acc0 + b;
    Y[(size_t)(r0 + 1) * DIM + tid] = acc1 + b;
    Y[(size_t)(r0 + 2) * DIM + tid] = acc2 + b;
    Y[(size_t)(r0 + 3) * DIM + tid] = acc3 + b;
}

// ---------------- K3: column sums / sumsq (for BatchNorm stats) -----------
__global__ __launch_bounds__(256) void k_stats(const float* __restrict__ Y,
                                               float* __restrict__ s1,
                                               float* __restrict__ s2) {
    // grid (8, 16): x = 64-col group, y = 64-row group
    int lc = threadIdx.x & 63;
    int lr = threadIdx.x >> 6;          // 0..3
    int col = blockIdx.x * 64 + lc;
    int r0  = blockIdx.y * 64 + lr;
    float a = 0.f, b = 0.f;
#pragma unroll
    for (int i = 0; i < 16; i++) {
        float v = Y[(size_t)(r0 + i * 4) * DIM + col];
        a += v;
        b += v * v;
    }
    atomicAdd(&s1[col], a);
    atomicAdd(&s2[col], b);
}

// ---------------- K4: BatchNorm + ReLU (in place) -------------------------
__global__ __launch_bounds__(256) void k_bnrelu(float* __restrict__ Y,
                                                const float* __restrict__ s1,
                                                const float* __restrict__ s2,
                                                const float* __restrict__ g,
                                                const float* __restrict__ beta) {
    int i = blockIdx.x * 256 + threadIdx.x;   // 524288 total
    int col = i & (DIM - 1);
    float m  = s1[col] * (1.0f / NB);
    float vv = s2[col] * (1.0f / NB) - m * m;
    float is = rsqrtf(vv + BN_EPS);
    float x = Y[i];
    float h = g[col] * (x - m) * is + beta[col];
    Y[i] = h > 0.f ? h : 0.f;
}

// ---------------- K5: final GEMM (1024x512 @ 512x52) + bias ---------------
__global__ __launch_bounds__(256) void k_gemm3(const float* __restrict__ A,
                                               const float* __restrict__ W,
                                               const float* __restrict__ bias,
                                               float* __restrict__ out) {
    __shared__ float As[4][DIM];
    int r0 = blockIdx.x * 4;
    int tid = threadIdx.x;
    for (int j = tid; j < 4 * DIM; j += 256) As[j >> 9][j & (DIM - 1)] = A[(size_t)r0 * DIM + j];
    __syncthreads();
    int col = tid & 63;
    int row = tid >> 6;
    if (col < NC) {
        float acc = 0.f;
        const float* wp = W + col;
#pragma unroll 4
        for (int k = 0; k < DIM; k++) acc += As[row][k] * wp[(size_t)k * NC];
        out[(size_t)(r0 + row) * NC + col] = acc + bias[col];
    }
}

extern "C" void kernel_launch(void* const* d_in, const int* in_sizes, int n_in,
                              void* d_out, int out_size, void* d_ws, size_t ws_size,
                              hipStream_t stream) {
    const float* z   = (const float*)d_in[0];
    const int*   bnn = (const int*)d_in[1];
    const float* w1  = (const float*)d_in[2];
    const float* b1  = (const float*)d_in[3];
    const float* g1  = (const float*)d_in[4];
    const float* be1 = (const float*)d_in[5];
    const float* w2  = (const float*)d_in[6];
    const float* b2  = (const float*)d_in[7];
    const float* g2  = (const float*)d_in[8];
    const float* be2 = (const float*)d_in[9];
    const float* w3  = (const float*)d_in[10];
    const float* b3  = (const float*)d_in[11];

    int*   offs  = (int*)d_ws;
    int*   cnt   = offs + 1024;
    float* inv   = (float*)(cnt + 1024);
    float* stats = inv + 1024;             // 2048 floats: s1a|s2a|s1b|s2b
    float* X     = stats + 2048;           // 1024*512
    float* Y1    = X  + (size_t)NB * DIM;
    float* Y2    = Y1 + (size_t)NB * DIM;
    float* out   = (float*)d_out;

    k_scan<<<1, 1024, 0, stream>>>(bnn, offs, cnt, inv, stats);
    k_pool<<<NB, 512, 0, stream>>>(z, offs, cnt, inv, X);

    k_gemm512<<<NB / 4, 512, 0, stream>>>(X, w1, b1, Y1);
    dim3 sg(8, 16);
    k_stats<<<sg, 256, 0, stream>>>(Y1, stats, stats + 512);
    k_bnrelu<<<(NB * DIM) / 256, 256, 0, stream>>>(Y1, stats, stats + 512, g1, be1);

    k_gemm512<<<NB / 4, 512, 0, stream>>>(Y1, w2, b2, Y2);
    k_stats<<<sg, 256, 0, stream>>>(Y2, stats + 1024, stats + 1536);
    k_bnrelu<<<(NB * DIM) / 256, 256, 0, stream>>>(Y2, stats + 1024, stats + 1536, g2, be2);

    k_gemm3<<<NB / 4, 256, 0, stream>>>(Y2, w3, b3, out);
}

// Round 2
// 711.863 us; speedup vs baseline: 1.1073x; 1.1073x over previous
//
#include <hip/hip_runtime.h>

#define N_TOTAL 204800
#define NB 1024
#define DIM 512
#define NC 52
#define BN_EPS 1e-5f

__device__ inline void f4add(float4& a, const float4 b) {
    a.x += b.x; a.y += b.y; a.z += b.z; a.w += b.w;
}

__device__ inline float bn_relu1(float v, int f,
                                 const float* __restrict__ s1, const float* __restrict__ s2,
                                 const float* __restrict__ g, const float* __restrict__ beta) {
    float m  = s1[f] * (1.0f / NB);
    float vv = s2[f] * (1.0f / NB) - m * m;
    float is = rsqrtf(vv + BN_EPS);
    float h  = g[f] * (v - m) * is + beta[f];
    return h > 0.f ? h : 0.f;
}

// ---------------- K0: prefix-scan of counts + dtype detect + zero stats ----
__global__ __launch_bounds__(1024) void k_scan(const int* __restrict__ bnn,
                                               int* __restrict__ offs,
                                               int* __restrict__ cnt,
                                               float* __restrict__ inv,
                                               float* __restrict__ stats /*2048 floats*/) {
    __shared__ int red[1024];
    int tid = threadIdx.x;
    int v32 = bnn[tid];
    red[tid] = v32;
    __syncthreads();
    for (int s = 512; s > 0; s >>= 1) {
        if (tid < s) red[tid] += red[tid + s];
        __syncthreads();
    }
    int total = red[0];
    __syncthreads();
    // if buffer is really int64 little-endian, low words sit at even int32 slots
    int c = (total == N_TOTAL) ? v32 : bnn[2 * tid];
    red[tid] = c;
    __syncthreads();
    for (int off = 1; off < 1024; off <<= 1) {
        int t = (tid >= off) ? red[tid - off] : 0;
        __syncthreads();
        red[tid] += t;
        __syncthreads();
    }
    offs[tid] = red[tid] - c;   // exclusive
    cnt[tid]  = c;
    inv[tid]  = 1.0f / (float)c;
    stats[tid]        = 0.0f;   // zero s1a,s2a,s1b,s2b
    stats[tid + 1024] = 0.0f;
}

// ---------------- K1: segment-mean pooling (float4) -----------------------
__global__ __launch_bounds__(256) void k_pool(const float* __restrict__ z,
                                              const int* __restrict__ offs,
                                              const int* __restrict__ cnt,
                                              const float* __restrict__ inv,
                                              float* __restrict__ X) {
    __shared__ float4 buf[128];
    int g = blockIdx.x;
    int s0 = offs[g];
    int n  = cnt[g];
    float r = inv[g];
    int c4 = threadIdx.x & 127;   // float4 column
    int rp = threadIdx.x >> 7;    // 0/1 row phase
    const float4* p = (const float4*)z + (size_t)s0 * 128 + c4;
    float4 a0 = {0,0,0,0}, a1 = {0,0,0,0}, a2 = {0,0,0,0}, a3 = {0,0,0,0};
    int i = rp;
    for (; i + 6 < n; i += 8) {
        float4 v0 = p[(size_t)(i + 0) * 128];
        float4 v1 = p[(size_t)(i + 2) * 128];
        float4 v2 = p[(size_t)(i + 4) * 128];
        float4 v3 = p[(size_t)(i + 6) * 128];
        f4add(a0, v0); f4add(a1, v1); f4add(a2, v2); f4add(a3, v3);
    }
    for (; i < n; i += 2) { float4 v = p[(size_t)i * 128]; f4add(a0, v); }
    f4add(a0, a1); f4add(a2, a3); f4add(a0, a2);
    if (rp == 1) buf[c4] = a0;
    __syncthreads();
    if (rp == 0) {
        f4add(a0, buf[c4]);
        a0.x *= r; a0.y *= r; a0.z *= r; a0.w *= r;
        ((float4*)X)[(size_t)g * 128 + c4] = a0;
    }
}

// ---------------- K2: 64x64 register-tiled GEMM, BN-in fused, stats-out ---
template <bool BNA>
__global__ __launch_bounds__(256) void k_gemm64(const float* __restrict__ A,
                                                const float* __restrict__ W,
                                                const float* __restrict__ bias,
                                                const float* __restrict__ ps1,
                                                const float* __restrict__ ps2,
                                                const float* __restrict__ gam,
                                                const float* __restrict__ bet,
                                                float* __restrict__ Y,
                                                float* __restrict__ os1,
                                                float* __restrict__ os2) {
    __shared__ float As[32][68];   // [k][row], padded
    __shared__ float Ws[32][68];   // [k][col], padded
    int tid = threadIdx.x;
    int tx = tid & 15, ty = tid >> 4;
    int gr0 = blockIdx.x * 64;
    int gc0 = blockIdx.y * 64;
    float acc[4][4] = {};

    for (int k0 = 0; k0 < DIM; k0 += 32) {
        // stage A transposed (apply BN+ReLU of previous layer if BNA)
#pragma unroll
        for (int it = 0; it < 2; it++) {
            int idx = it * 256 + tid;
            int row = idx >> 3;
            int kq  = idx & 7;
            int f0  = k0 + kq * 4;
            float4 v = *(const float4*)&A[(size_t)(gr0 + row) * DIM + f0];
            if (BNA) {
                v.x = bn_relu1(v.x, f0 + 0, ps1, ps2, gam, bet);
                v.y = bn_relu1(v.y, f0 + 1, ps1, ps2, gam, bet);
                v.z = bn_relu1(v.z, f0 + 2, ps1, ps2, gam, bet);
                v.w = bn_relu1(v.w, f0 + 3, ps1, ps2, gam, bet);
            }
            As[kq * 4 + 0][row] = v.x;
            As[kq * 4 + 1][row] = v.y;
            As[kq * 4 + 2][row] = v.z;
            As[kq * 4 + 3][row] = v.w;
        }
        // stage W
#pragma unroll
        for (int it = 0; it < 2; it++) {
            int idx = it * 256 + tid;
            int k  = idx >> 4;
            int cq = idx & 15;
            *(float4*)&Ws[k][cq * 4] =
                *(const float4*)&W[(size_t)(k0 + k) * DIM + gc0 + cq * 4];
        }
        __syncthreads();
#pragma unroll
        for (int k = 0; k < 32; k++) {
            float4 a = *(const float4*)&As[k][ty * 4];
            float4 w = *(const float4*)&Ws[k][tx * 4];
            acc[0][0] += a.x * w.x; acc[0][1] += a.x * w.y; acc[0][2] += a.x * w.z; acc[0][3] += a.x * w.w;
            acc[1][0] += a.y * w.x; acc[1][1] += a.y * w.y; acc[1][2] += a.y * w.z; acc[1][3] += a.y * w.w;
            acc[2][0] += a.z * w.x; acc[2][1] += a.z * w.y; acc[2][2] += a.z * w.z; acc[2][3] += a.z * w.w;
            acc[3][0] += a.w * w.x; acc[3][1] += a.w * w.y; acc[3][2] += a.w * w.z; acc[3][3] += a.w * w.w;
        }
        __syncthreads();
    }

    // epilogue: +bias, store, column stats via atomics
    float4 b = *(const float4*)&bias[gc0 + tx * 4];
    float s[4] = {}, q[4] = {};
#pragma unroll
    for (int i = 0; i < 4; i++) {
        float4 y;
        y.x = acc[i][0] + b.x;
        y.y = acc[i][1] + b.y;
        y.z = acc[i][2] + b.z;
        y.w = acc[i][3] + b.w;
        *(float4*)&Y[(size_t)(gr0 + ty * 4 + i) * DIM + gc0 + tx * 4] = y;
        s[0] += y.x; q[0] += y.x * y.x;
        s[1] += y.y; q[1] += y.y * y.y;
        s[2] += y.z; q[2] += y.z * y.z;
        s[3] += y.w; q[3] += y.w * y.w;
    }
#pragma unroll
    for (int j = 0; j < 4; j++) {
        atomicAdd(&os1[gc0 + tx * 4 + j], s[j]);
        atomicAdd(&os2[gc0 + tx * 4 + j], q[j]);
    }
}

// ---------------- K3: final GEMM (BN2 fused on input) ---------------------
__global__ __launch_bounds__(256) void k_gemm3(const float* __restrict__ Y2,
                                               const float* __restrict__ W,
                                               const float* __restrict__ bias,
                                               const float* __restrict__ s1,
                                               const float* __restrict__ s2,
                                               const float* __restrict__ gam,
                                               const float* __restrict__ bet,
                                               float* __restrict__ out) {
    __shared__ float As[4][DIM];
    int tid = threadIdx.x;
    int r0 = blockIdx.x * 4;
#pragma unroll
    for (int it = 0; it < 2; it++) {
        int idx = it * 256 + tid;
        int row = idx >> 7;
        int cq  = idx & 127;
        int f   = cq * 4;
        float4 v = *(const float4*)&Y2[(size_t)(r0 + row) * DIM + f];
        v.x = bn_relu1(v.x, f + 0, s1, s2, gam, bet);
        v.y = bn_relu1(v.y, f + 1, s1, s2, gam, bet);
        v.z = bn_relu1(v.z, f + 2, s1, s2, gam, bet);
        v.w = bn_relu1(v.w, f + 3, s1, s2, gam, bet);
        *(float4*)&As[row][f] = v;
    }
    __syncthreads();
    int col = tid & 63;
    int row = tid >> 6;
    if (col < NC) {
        float acc = 0.f;
#pragma unroll 8
        for (int k = 0; k < DIM; k += 4) {
            float4 a = *(const float4*)&As[row][k];
            acc += a.x * W[(size_t)(k + 0) * NC + col];
            acc += a.y * W[(size_t)(k + 1) * NC + col];
            acc += a.z * W[(size_t)(k + 2) * NC + col];
            acc += a.w * W[(size_t)(k + 3) * NC + col];
        }
        out[(size_t)(r0 + row) * NC + col] = acc + bias[col];
    }
}

extern "C" void kernel_launch(void* const* d_in, const int* in_sizes, int n_in,
                              void* d_out, int out_size, void* d_ws, size_t ws_size,
                              hipStream_t stream) {
    const float* z   = (const float*)d_in[0];
    const int*   bnn = (const int*)d_in[1];
    const float* w1  = (const float*)d_in[2];
    const float* b1  = (const float*)d_in[3];
    const float* g1  = (const float*)d_in[4];
    const float* be1 = (const float*)d_in[5];
    const float* w2  = (const float*)d_in[6];
    const float* b2  = (const float*)d_in[7];
    const float* g2  = (const float*)d_in[8];
    const float* be2 = (const float*)d_in[9];
    const float* w3  = (const float*)d_in[10];
    const float* b3  = (const float*)d_in[11];

    int*   offs  = (int*)d_ws;
    int*   cnt   = offs + 1024;
    float* inv   = (float*)(cnt + 1024);
    float* stats = inv + 1024;             // 2048 floats: s1a|s2a|s1b|s2b
    float* X     = stats + 2048;
    float* Y1    = X  + (size_t)NB * DIM;
    float* Y2    = Y1 + (size_t)NB * DIM;
    float* out   = (float*)d_out;

    k_scan<<<1, 1024, 0, stream>>>(bnn, offs, cnt, inv, stats);
    k_pool<<<NB, 256, 0, stream>>>(z, offs, cnt, inv, X);

    dim3 gg(NB / 64, DIM / 64);
    // layer 1: no BN on input; stats out -> s1a,s2a
    k_gemm64<false><<<gg, 256, 0, stream>>>(X, w1, b1,
                                            nullptr, nullptr, nullptr, nullptr,
                                            Y1, stats, stats + 512);
    // layer 2: BN1+ReLU fused on input; stats out -> s1b,s2b
    k_gemm64<true><<<gg, 256, 0, stream>>>(Y1, w2, b2,
                                           stats, stats + 512, g1, be1,
                                           Y2, stats + 1024, stats + 1536);
    // layer 3: BN2+ReLU fused on input
    k_gemm3<<<NB / 4, 256, 0, stream>>>(Y2, w3, b3,
                                        stats + 1024, stats + 1536, g2, be2, out);
}

// Round 3
// 658.082 us; speedup vs baseline: 1.1978x; 1.0817x over previous
//
#include <hip/hip_runtime.h>

#define N_TOTAL 204800
#define NB 1024
#define DIM 512
#define NC 52
#define BN_EPS 1e-5f

__device__ inline void f4add(float4& a, const float4 b) {
    a.x += b.x; a.y += b.y; a.z += b.z; a.w += b.w;
}

__device__ inline float bn_relu1(float v, int f,
                                 const float* __restrict__ s1, const float* __restrict__ s2,
                                 const float* __restrict__ g, const float* __restrict__ beta) {
    float m  = s1[f] * (1.0f / NB);
    float vv = s2[f] * (1.0f / NB) - m * m;
    float is = rsqrtf(vv + BN_EPS);
    float h  = g[f] * (v - m) * is + beta[f];
    return h > 0.f ? h : 0.f;
}

// ---------------- K0: prefix-scan of counts + dtype detect + zero stats ----
__global__ __launch_bounds__(1024) void k_scan(const int* __restrict__ bnn,
                                               int* __restrict__ offs,
                                               int* __restrict__ cnt,
                                               float* __restrict__ inv,
                                               float* __restrict__ stats /*2048 floats*/) {
    __shared__ int red[1024];
    int tid = threadIdx.x;
    int v32 = bnn[tid];
    red[tid] = v32;
    __syncthreads();
    for (int s = 512; s > 0; s >>= 1) {
        if (tid < s) red[tid] += red[tid + s];
        __syncthreads();
    }
    int total = red[0];
    __syncthreads();
    // if buffer is really int64 little-endian, low words sit at even int32 slots
    int c = (total == N_TOTAL) ? v32 : bnn[2 * tid];
    red[tid] = c;
    __syncthreads();
    for (int off = 1; off < 1024; off <<= 1) {
        int t = (tid >= off) ? red[tid - off] : 0;
        __syncthreads();
        red[tid] += t;
        __syncthreads();
    }
    offs[tid] = red[tid] - c;   // exclusive
    cnt[tid]  = c;
    inv[tid]  = 1.0f / (float)c;
    stats[tid]        = 0.0f;   // zero s1a,s2a,s1b,s2b
    stats[tid + 1024] = 0.0f;
}

// ---------------- K1: segment-mean pooling (float4, 8 loads in flight) ----
__global__ __launch_bounds__(256) void k_pool(const float* __restrict__ z,
                                              const int* __restrict__ offs,
                                              const int* __restrict__ cnt,
                                              const float* __restrict__ inv,
                                              float* __restrict__ X) {
    __shared__ float4 buf[128];
    int g = blockIdx.x;
    int s0 = offs[g];
    int n  = cnt[g];
    float r = inv[g];
    int c4 = threadIdx.x & 127;   // float4 column
    int rp = threadIdx.x >> 7;    // 0/1 row phase
    const float4* p = (const float4*)z + (size_t)s0 * 128 + c4;
    float4 a0 = {0,0,0,0}, a1 = {0,0,0,0}, a2 = {0,0,0,0}, a3 = {0,0,0,0};
    int i = rp;
    for (; i + 14 < n; i += 16) {
        float4 v0 = p[(size_t)(i + 0) * 128];
        float4 v1 = p[(size_t)(i + 2) * 128];
        float4 v2 = p[(size_t)(i + 4) * 128];
        float4 v3 = p[(size_t)(i + 6) * 128];
        float4 v4 = p[(size_t)(i + 8) * 128];
        float4 v5 = p[(size_t)(i + 10) * 128];
        float4 v6 = p[(size_t)(i + 12) * 128];
        float4 v7 = p[(size_t)(i + 14) * 128];
        f4add(a0, v0); f4add(a1, v1); f4add(a2, v2); f4add(a3, v3);
        f4add(a0, v4); f4add(a1, v5); f4add(a2, v6); f4add(a3, v7);
    }
    for (; i < n; i += 2) { float4 v = p[(size_t)i * 128]; f4add(a0, v); }
    f4add(a0, a1); f4add(a2, a3); f4add(a0, a2);
    if (rp == 1) buf[c4] = a0;
    __syncthreads();
    if (rp == 0) {
        f4add(a0, buf[c4]);
        a0.x *= r; a0.y *= r; a0.z *= r; a0.w *= r;
        ((float4*)X)[(size_t)g * 128 + c4] = a0;
    }
}

// ---------------- K2: 32x64 tiled GEMM, reg-prefetch, BN-in, stats-out ----
// grid (NB/32, DIM/64) = 256 blocks (1/CU), 256 threads
template <bool BNA>
__global__ __launch_bounds__(256) void k_gemm32x64(const float* __restrict__ A,
                                                   const float* __restrict__ W,
                                                   const float* __restrict__ bias,
                                                   const float* __restrict__ ps1,
                                                   const float* __restrict__ ps2,
                                                   const float* __restrict__ gam,
                                                   const float* __restrict__ bet,
                                                   float* __restrict__ Y,
                                                   float* __restrict__ os1,
                                                   float* __restrict__ os2) {
    __shared__ float As[32][34];   // [k][row], pad 34 (even -> b64-aligned rows)
    __shared__ float Ws[32][68];   // [k][col], pad 68 (16B-aligned rows)
    int tid = threadIdx.x;
    int tx = tid & 15, ty = tid >> 4;
    int gr0 = blockIdx.x * 32;
    int gc0 = blockIdx.y * 64;

    // A-staging coords: 256 float4 = 32 rows x 8 k-quads
    int arow = tid >> 3;          // 0..31
    int akq  = tid & 7;           // 0..7
    // W-staging coords: 512 float4 = 32 k x 16 col-quads, 2 per thread
    int wk0 = tid >> 4;           // 0..15  (first half rows)
    int wcq = tid & 15;           // 0..15

    float acc[2][4] = {};

    // prefetch tile 0
    float4 ra  = *(const float4*)&A[(size_t)(gr0 + arow) * DIM + akq * 4];
    float4 rw0 = *(const float4*)&W[(size_t)wk0 * DIM + gc0 + wcq * 4];
    float4 rw1 = *(const float4*)&W[(size_t)(wk0 + 16) * DIM + gc0 + wcq * 4];

    for (int kt = 0; kt < 16; kt++) {
        // store staged regs to LDS (BN+ReLU applied to A here)
        float4 v = ra;
        if (BNA) {
            int f0 = kt * 32 + akq * 4;
            v.x = bn_relu1(v.x, f0 + 0, ps1, ps2, gam, bet);
            v.y = bn_relu1(v.y, f0 + 1, ps1, ps2, gam, bet);
            v.z = bn_relu1(v.z, f0 + 2, ps1, ps2, gam, bet);
            v.w = bn_relu1(v.w, f0 + 3, ps1, ps2, gam, bet);
        }
        As[akq * 4 + 0][arow] = v.x;
        As[akq * 4 + 1][arow] = v.y;
        As[akq * 4 + 2][arow] = v.z;
        As[akq * 4 + 3][arow] = v.w;
        *(float4*)&Ws[wk0][wcq * 4]      = rw0;
        *(float4*)&Ws[wk0 + 16][wcq * 4] = rw1;
        __syncthreads();

        if (kt < 15) {
            int k0 = (kt + 1) * 32;
            ra  = *(const float4*)&A[(size_t)(gr0 + arow) * DIM + k0 + akq * 4];
            rw0 = *(const float4*)&W[(size_t)(k0 + wk0) * DIM + gc0 + wcq * 4];
            rw1 = *(const float4*)&W[(size_t)(k0 + wk0 + 16) * DIM + gc0 + wcq * 4];
        }

#pragma unroll
        for (int k = 0; k < 32; k++) {
            float2 a = *(const float2*)&As[k][ty * 2];
            float4 w = *(const float4*)&Ws[k][tx * 4];
            acc[0][0] += a.x * w.x; acc[0][1] += a.x * w.y;
            acc[0][2] += a.x * w.z; acc[0][3] += a.x * w.w;
            acc[1][0] += a.y * w.x; acc[1][1] += a.y * w.y;
            acc[1][2] += a.y * w.z; acc[1][3] += a.y * w.w;
        }
        __syncthreads();
    }

    // epilogue: +bias, store, column stats (wave-reduced, then atomics)
    float4 b = *(const float4*)&bias[gc0 + tx * 4];
    float s[4] = {}, q[4] = {};
#pragma unroll
    for (int i = 0; i < 2; i++) {
        float4 y;
        y.x = acc[i][0] + b.x;
        y.y = acc[i][1] + b.y;
        y.z = acc[i][2] + b.z;
        y.w = acc[i][3] + b.w;
        *(float4*)&Y[(size_t)(gr0 + ty * 2 + i) * DIM + gc0 + tx * 4] = y;
        s[0] += y.x; q[0] += y.x * y.x;
        s[1] += y.y; q[1] += y.y * y.y;
        s[2] += y.z; q[2] += y.z * y.z;
        s[3] += y.w; q[3] += y.w * y.w;
    }
    // reduce across the 4 ty values within each wave (lanes differ by 16, 32)
#pragma unroll
    for (int j = 0; j < 4; j++) {
        s[j] += __shfl_xor(s[j], 16); s[j] += __shfl_xor(s[j], 32);
        q[j] += __shfl_xor(q[j], 16); q[j] += __shfl_xor(q[j], 32);
    }
    if ((ty & 3) == 0) {
#pragma unroll
        for (int j = 0; j < 4; j++) {
            atomicAdd(&os1[gc0 + tx * 4 + j], s[j]);
            atomicAdd(&os2[gc0 + tx * 4 + j], q[j]);
        }
    }
}

// ---------------- K3: final GEMM (BN2 fused on input) ---------------------
__global__ __launch_bounds__(256) void k_gemm3(const float* __restrict__ Y2,
                                               const float* __restrict__ W,
                                               const float* __restrict__ bias,
                                               const float* __restrict__ s1,
                                               const float* __restrict__ s2,
                                               const float* __restrict__ gam,
                                               const float* __restrict__ bet,
                                               float* __restrict__ out) {
    __shared__ float As[4][DIM];
    int tid = threadIdx.x;
    int r0 = blockIdx.x * 4;
#pragma unroll
    for (int it = 0; it < 2; it++) {
        int idx = it * 256 + tid;
        int row = idx >> 7;
        int cq  = idx & 127;
        int f   = cq * 4;
        float4 v = *(const float4*)&Y2[(size_t)(r0 + row) * DIM + f];
        v.x = bn_relu1(v.x, f + 0, s1, s2, gam, bet);
        v.y = bn_relu1(v.y, f + 1, s1, s2, gam, bet);
        v.z = bn_relu1(v.z, f + 2, s1, s2, gam, bet);
        v.w = bn_relu1(v.w, f + 3, s1, s2, gam, bet);
        *(float4*)&As[row][f] = v;
    }
    __syncthreads();
    int col = tid & 63;
    int row = tid >> 6;
    if (col < NC) {
        float acc = 0.f;
#pragma unroll 8
        for (int k = 0; k < DIM; k += 4) {
            float4 a = *(const float4*)&As[row][k];
            acc += a.x * W[(size_t)(k + 0) * NC + col];
            acc += a.y * W[(size_t)(k + 1) * NC + col];
            acc += a.z * W[(size_t)(k + 2) * NC + col];
            acc += a.w * W[(size_t)(k + 3) * NC + col];
        }
        out[(size_t)(r0 + row) * NC + col] = acc + bias[col];
    }
}

extern "C" void kernel_launch(void* const* d_in, const int* in_sizes, int n_in,
                              void* d_out, int out_size, void* d_ws, size_t ws_size,
                              hipStream_t stream) {
    const float* z   = (const float*)d_in[0];
    const int*   bnn = (const int*)d_in[1];
    const float* w1  = (const float*)d_in[2];
    const float* b1  = (const float*)d_in[3];
    const float* g1  = (const float*)d_in[4];
    const float* be1 = (const float*)d_in[5];
    const float* w2  = (const float*)d_in[6];
    const float* b2  = (const float*)d_in[7];
    const float* g2  = (const float*)d_in[8];
    const float* be2 = (const float*)d_in[9];
    const float* w3  = (const float*)d_in[10];
    const float* b3  = (const float*)d_in[11];

    int*   offs  = (int*)d_ws;
    int*   cnt   = offs + 1024;
    float* inv   = (float*)(cnt + 1024);
    float* stats = inv + 1024;             // 2048 floats: s1a|s2a|s1b|s2b
    float* X     = stats + 2048;
    float* Y1    = X  + (size_t)NB * DIM;
    float* Y2    = Y1 + (size_t)NB * DIM;
    float* out   = (float*)d_out;

    k_scan<<<1, 1024, 0, stream>>>(bnn, offs, cnt, inv, stats);
    k_pool<<<NB, 256, 0, stream>>>(z, offs, cnt, inv, X);

    dim3 gg(NB / 32, DIM / 64);
    // layer 1: no BN on input; stats out -> s1a,s2a
    k_gemm32x64<false><<<gg, 256, 0, stream>>>(X, w1, b1,
                                               nullptr, nullptr, nullptr, nullptr,
                                               Y1, stats, stats + 512);
    // layer 2: BN1+ReLU fused on input; stats out -> s1b,s2b
    k_gemm32x64<true><<<gg, 256, 0, stream>>>(Y1, w2, b2,
                                              stats, stats + 512, g1, be1,
                                              Y2, stats + 1024, stats + 1536);
    // layer 3: BN2+ReLU fused on input
    k_gemm3<<<NB / 4, 256, 0, stream>>>(Y2, w3, b3,
                                        stats + 1024, stats + 1536, g2, be2, out);
}